// Round 5
// baseline (20235.765 us; speedup 1.0000x reference)
//
#include <hip/hip_runtime.h>
#include <hip/hip_bf16.h>
#include <math.h>

#define E_DIM 1024
#define FF_DIM 4096
#define LAYERS 24
#define MPAD 320      // 20 * 16 token-row padding (rows 257..319 zero / ignored)
#define SPAD 288      // vT / P column padding (9 * 32)
#define KCP 608       // conv K (588) padded to 19*32
#define NB 256        // persistent grid blocks (1-2 per CU, co-residency guaranteed)

typedef __attribute__((ext_vector_type(8))) short short8;
typedef __attribute__((ext_vector_type(8))) __bf16 bf16x8;
typedef __attribute__((ext_vector_type(4))) float float4_t;
typedef __attribute__((ext_vector_type(4))) unsigned short ushort4_t;

union ABu { short8 s; bf16x8 b; };
union BFU { __bf16 b; unsigned short u; };

__device__ __forceinline__ float4_t MFMA(bf16x8 a, bf16x8 b, float4_t c) {
  return __builtin_amdgcn_mfma_f32_16x16x32_bf16(a, b, c, 0, 0, 0);
}
__device__ __forceinline__ float4_t MFMAs(short8 a, short8 b, float4_t c) {
  ABu ua, ub; ua.s = a; ub.s = b;
  return __builtin_amdgcn_mfma_f32_16x16x32_bf16(ua.b, ub.b, c, 0, 0, 0);
}
__device__ __forceinline__ unsigned short f2bf(float f) {
  BFU x; x.b = (__bf16)f; return x.u;
}

struct MegaParams {
  const float *frame, *bboxes, *conv_w, *cls_emb;
  const float *ln1_s, *ln1_b;
  const float *wq, *bq, *wk, *bk, *wv, *bv, *wo, *bo;
  const float *ln2_s, *ln2_b, *w1, *b1, *w2, *b2;
  float* x;
  unsigned short *h, *qb, *kb, *vT, *ob, *mb;
  float *part, *pbv, *Mi;
  unsigned short *Pm, *Wp;
  float* out;
  unsigned* bar;
};

// ---------------------------------------------------------------------------
// Device-wide sense-reversing barrier. Requires all NB blocks co-resident
// (grid 256 <= 1 block/CU capacity; launch_bounds(256,2) gives 2/CU).
// bar[0]=arrive count, bar[1]=generation. All-thread fences for L1 coherence.
// ---------------------------------------------------------------------------
__device__ __forceinline__ void gsync(unsigned* bar) {
  __threadfence();      // publish this block's writes (device scope)
  __syncthreads();
  if (threadIdx.x == 0) {
    unsigned gen = __hip_atomic_load(&bar[1], __ATOMIC_RELAXED, __HIP_MEMORY_SCOPE_AGENT);
    unsigned a = __hip_atomic_fetch_add(&bar[0], 1u, __ATOMIC_ACQ_REL, __HIP_MEMORY_SCOPE_AGENT);
    if (a == (unsigned)NB - 1u) {
      __hip_atomic_store(&bar[0], 0u, __ATOMIC_RELAXED, __HIP_MEMORY_SCOPE_AGENT);
      __hip_atomic_fetch_add(&bar[1], 1u, __ATOMIC_ACQ_REL, __HIP_MEMORY_SCOPE_AGENT);
    } else {
      while (__hip_atomic_load(&bar[1], __ATOMIC_ACQUIRE, __HIP_MEMORY_SCOPE_AGENT) == gen)
        __builtin_amdgcn_s_sleep(1);
    }
  }
  __syncthreads();
  __threadfence();      // acquire: invalidate L1 so post-barrier reads are fresh
}

// ---------------------------------------------------------------------------
// Phase: prep (im2col, weight repack, pad zeroing) — grid-stride over elements
// ---------------------------------------------------------------------------
__device__ void phase_prep(const MegaParams& P, int gtid) {
  for (int i = gtid; i < 256 * KCP; i += NB * 256) {
    int b = i / KCP, kk = i - b * KCP;
    unsigned short us = 0;
    if (kk < 588) {
      int c = kk / 196, rem = kk % 196;
      int pr = b >> 4, pc = b & 15;
      int ii = rem / 14, jj = rem % 14;
      us = f2bf(P.frame[c * 224 * 224 + (pr * 14 + ii) * 224 + (pc * 14 + jj)]);
    }
    P.Pm[i] = us;
  }
  for (int i = gtid; i < 1024 * KCP; i += NB * 256) {
    int n = i / KCP, kk = i - n * KCP;
    P.Wp[i] = (kk < 588) ? f2bf(P.conv_w[n * 588 + kk]) : (unsigned short)0;
  }
  const int NH = (MPAD - 257) * E_DIM;
  const int NO = (MPAD - 272) * E_DIM;
  const int NV = 16 * 64 * (SPAD - 272);
  for (int i = gtid; i < NH + NO + NV; i += NB * 256) {
    if (i < NH) P.h[257 * E_DIM + i] = 0;
    else if (i < NH + NO) P.ob[272 * E_DIM + (i - NH)] = 0;
    else {
      int k = i - NH - NO;
      P.vT[(size_t)(k >> 4) * SPAD + 272 + (k & 15)] = 0;
    }
  }
}

// ---------------------------------------------------------------------------
// Phase: pb_cls (one block)
// ---------------------------------------------------------------------------
__device__ void phase_pbcls(const MegaParams& P, char* smem, int tid) {
  float* sb = (float*)smem;          // 128
  float* red = sb + 128;             // 256
  if (tid < 128) sb[tid] = P.bboxes[tid];
  __syncthreads();
  int p = tid;
  float px1 = (float)((p & 15) * 14), py1 = (float)((p >> 4) * 14);
  float px2 = px1 + 14.f, py2 = py1 + 14.f;
  float s = 0.f;
  for (int r = 0; r < 32; ++r) {
    float bx1 = sb[r * 4 + 0], by1 = sb[r * 4 + 1], bx2 = sb[r * 4 + 2], by2 = sb[r * 4 + 3];
    float iw = fmaxf(fminf(bx2, px2) - fmaxf(bx1, px1), 0.f);
    float ih = fmaxf(fminf(by2, py2) - fmaxf(by1, py1), 0.f);
    float ov = iw * ih * (1.f / 196.f);
    P.Mi[r * 256 + p] = ov;
    s += ov;
  }
  red[tid] = s;
  __syncthreads();
  for (int off = 128; off > 0; off >>= 1) {
    if (tid < off) red[tid] = fmaxf(red[tid], red[tid + off]);
    __syncthreads();
  }
  P.pbv[p] = s / (red[0] + 1e-6f);
  for (int j = 0; j < 4; ++j) P.x[tid * 4 + j] = P.cls_emb[tid * 4 + j];
}

// ---------------------------------------------------------------------------
// Phase: conv GEMM (blocks 0..63)
// ---------------------------------------------------------------------------
__device__ void phase_conv(const MegaParams& P, int vb, int tid) {
  int n0 = vb * 16;
  int wave = tid >> 6, lane = tid & 63;
  int lg = lane >> 4, lc = lane & 15;
  float4_t acc[4] = {{0,0,0,0},{0,0,0,0},{0,0,0,0},{0,0,0,0}};
  const unsigned short* bp = P.Wp + (size_t)(n0 + lc) * KCP + lg * 8;
  const unsigned short* apt[4];
#pragma unroll
  for (int t = 0; t < 4; ++t) apt[t] = P.Pm + (size_t)((wave + t * 4) * 16 + lc) * KCP + lg * 8;
  for (int s = 0; s < 19; ++s) {
    short8 bf = *(const short8*)bp; bp += 32;
#pragma unroll
    for (int t = 0; t < 4; ++t) {
      short8 af = *(const short8*)apt[t]; apt[t] += 32;
      acc[t] = MFMAs(af, bf, acc[t]);
    }
  }
#pragma unroll
  for (int t = 0; t < 4; ++t) {
    int mbase = (wave + t * 4) * 16 + lg * 4;
#pragma unroll
    for (int r = 0; r < 4; ++r)
      P.x[(size_t)(1 + mbase + r) * E_DIM + n0 + lc] = fmaxf(acc[t][r], 0.f);
  }
}

// ---------------------------------------------------------------------------
// Phase: residual-reduce + LayerNorm for one token row m
// ---------------------------------------------------------------------------
__device__ void phase_ln(float* x, const float* part, int nparts, const float* rbias,
                         const float* lns, const float* lnb, unsigned short* hout,
                         int m, int tid, char* smem) {
  float* red = (float*)smem;   // 8 floats
  int c0 = tid * 4;
  float4_t v = *(const float4_t*)(x + (size_t)m * E_DIM + c0);
  if (rbias) v += *(const float4_t*)(rbias + c0);
  for (int s = 0; s < nparts; ++s)
    v += *(const float4_t*)(part + ((size_t)s * MPAD + m) * E_DIM + c0);
  if (nparts > 0) *(float4_t*)(x + (size_t)m * E_DIM + c0) = v;
  float s1 = v[0] + v[1] + v[2] + v[3];
  float s2 = v[0] * v[0] + v[1] * v[1] + v[2] * v[2] + v[3] * v[3];
#pragma unroll
  for (int off = 1; off < 64; off <<= 1) {
    s1 += __shfl_xor(s1, off, 64);
    s2 += __shfl_xor(s2, off, 64);
  }
  int wave = tid >> 6, lane = tid & 63;
  if (lane == 0) { red[wave * 2] = s1; red[wave * 2 + 1] = s2; }
  __syncthreads();
  s1 = red[0] + red[2] + red[4] + red[6];
  s2 = red[1] + red[3] + red[5] + red[7];
  float mean = s1 * (1.f / 1024.f);
  float var = s2 * (1.f / 1024.f) - mean * mean;
  float rstd = rsqrtf(var + 1e-5f);
  float4_t ls = *(const float4_t*)(lns + c0);
  float4_t lb = *(const float4_t*)(lnb + c0);
  ushort4_t hv;
#pragma unroll
  for (int r = 0; r < 4; ++r) hv[r] = f2bf((v[r] - mean) * rstd * ls[r] + lb[r]);
  *(ushort4_t*)(hout + (size_t)m * E_DIM + c0) = hv;
  __syncthreads();   // red reuse safety for strided items
}

// ---------------------------------------------------------------------------
// GEMM phase: C[m][n] = A[m][:] (bf16) . W[:][n] (fp32->bf16)
// item = (nt, ks): 16 N-cols x ALL 320 M-rows x K-chunk (NK x BK128)
// LDS double-buffered weight tile, 2-tile-deep register prefetch.
// EPI 0: q/k/vT scatter (+bias)  EPI 1: quickgelu (+bias)  EPI 2: fp32 partial
// ---------------------------------------------------------------------------
template <int NTOT, int EPI, int NK>
__device__ void phase_gemm(char* smem, int vb, int NITEMS, int NT,
                           const unsigned short* A, int lda,
                           const float* Wa, const float* Wb2, const float* Wc,
                           const float* ba, const float* bb, const float* bc,
                           unsigned short* oq, unsigned short* okk,
                           unsigned short* ovT, unsigned short* om,
                           float* opart, int tid) {
  if (vb >= NITEMS) return;
  float* Wt = (float*)smem;   // [2][128][16]
  int nt = vb % NT, ks = vb / NT;
  int wave = tid >> 6, lane = tid & 63;
  int lg = lane >> 4, lc = lane & 15;

  const float* W; const float* bias; int ncol;
  if (EPI == 0) {
    int sel = nt >> 6; ncol = (nt & 63) << 4;
    W = (sel == 0) ? Wa : ((sel == 1) ? Wb2 : Wc);
    bias = (sel == 0) ? ba : ((sel == 1) ? bb : bc);
  } else {
    ncol = nt << 4; W = Wa; bias = ba;
  }

  const int kb0 = ks * (NK * 128);
  const float* wsrc = W + (size_t)(kb0 + wave * 32 + (lane >> 2)) * NTOT + ncol + (lane & 3) * 4;
  const int wdoff = (wave * 32 + (lane >> 2)) * 16 + (lane & 3) * 4;

  const unsigned short* ap[5];
#pragma unroll
  for (int j = 0; j < 5; ++j)
    ap[j] = A + (size_t)((wave + 4 * j) * 16 + lc) * lda + kb0 + lg * 8;

  float4_t acc[5] = {{0,0,0,0},{0,0,0,0},{0,0,0,0},{0,0,0,0},{0,0,0,0}};
  float4_t s0, s1, s2, s3;

  // prologue: tile0 -> buf0; issue loads for tile1 (and tile2 if NK>2)
  s0 = *(const float4_t*)wsrc;
  s1 = *(const float4_t*)(wsrc + (size_t)16 * NTOT);
  wsrc += (size_t)128 * NTOT;
  *(float4_t*)(Wt + wdoff) = s0;
  *(float4_t*)(Wt + wdoff + 256) = s1;
  s0 = *(const float4_t*)wsrc;
  s1 = *(const float4_t*)(wsrc + (size_t)16 * NTOT);
  wsrc += (size_t)128 * NTOT;
  if (NK > 2) {
    s2 = *(const float4_t*)wsrc;
    s3 = *(const float4_t*)(wsrc + (size_t)16 * NTOT);
    wsrc += (size_t)128 * NTOT;
  }

  for (int t = 0; t < NK; ++t) {
    __syncthreads();
    if (t + 1 < NK) {
      float* d = Wt + ((t + 1) & 1) * 2048 + wdoff;
      *(float4_t*)d = s0;
      *(float4_t*)(d + 256) = s1;
      s0 = s2; s1 = s3;
      if (t + 3 < NK) {
        s2 = *(const float4_t*)wsrc;
        s3 = *(const float4_t*)(wsrc + (size_t)16 * NTOT);
        wsrc += (size_t)128 * NTOT;
      }
    }
    const float* Wb_ = Wt + (t & 1) * 2048;
#pragma unroll
    for (int s = 0; s < 4; ++s) {
      float wv[8];
#pragma unroll
      for (int i = 0; i < 8; ++i) wv[i] = Wb_[(s * 32 + lg * 8 + i) * 16 + lc];
      bf16x8 wf;
#pragma unroll
      for (int i = 0; i < 8; ++i) wf[i] = (__bf16)wv[i];
#pragma unroll
      for (int j = 0; j < 5; ++j) {
        ABu a; a.s = *(const short8*)ap[j]; ap[j] += 32;
        acc[j] = MFMA(wf, a.b, acc[j]);
      }
    }
  }

  float4_t bvv = {0,0,0,0};
  if (bias) bvv = *(const float4_t*)(bias + ncol + lg * 4);

  if (EPI == 0) {
    int sel = nt >> 6;
    int head = ncol >> 6;
    int dbase = (ncol & 63) + lg * 4;
#pragma unroll
    for (int j = 0; j < 5; ++j) {
      int tile = wave + 4 * j;
      int m = tile * 16 + lc;
      if (sel < 2) {
        unsigned short* dst = (sel == 0 ? oq : okk) + ((size_t)(head * MPAD + m)) * 64 + dbase;
        ushort4_t hv;
#pragma unroll
        for (int r = 0; r < 4; ++r) hv[r] = f2bf(acc[j][r] + bvv[r]);
        *(ushort4_t*)dst = hv;
      } else if (tile < 17) {
#pragma unroll
        for (int r = 0; r < 4; ++r)
          ovT[(size_t)(head * 64 + dbase + r) * SPAD + m] = f2bf(acc[j][r] + bvv[r]);
      }
    }
  } else if (EPI == 1) {
#pragma unroll
    for (int j = 0; j < 5; ++j) {
      int m = (wave + 4 * j) * 16 + lc;
      ushort4_t hv;
#pragma unroll
      for (int r = 0; r < 4; ++r) {
        float v = acc[j][r] + bvv[r];
        v = v / (1.f + __expf(-1.702f * v));
        hv[r] = f2bf(v);
      }
      *(ushort4_t*)(om + (size_t)m * FF_DIM + ncol + lg * 4) = hv;
    }
  } else {
#pragma unroll
    for (int j = 0; j < 5; ++j) {
      int m = (wave + 4 * j) * 16 + lc;
      *(float4_t*)(opart + ((size_t)ks * MPAD + m) * E_DIM + ncol + lg * 4) = acc[j];
    }
  }
}

// ---------------------------------------------------------------------------
// Attention phase: item v = head*17 + qtile
// ---------------------------------------------------------------------------
__device__ void phase_attn(const MegaParams& P, char* smem, int v, int tid) {
  float* smax = (float*)smem;                       // 64
  float* sden = smax + 64;                          // 64
  unsigned short* Pl = (unsigned short*)(sden + 64); // 16*288, 16B-aligned (512B off)
  int head = v / 17, qt = v % 17;
  int q0 = qt * 16;
  int wave = tid >> 6, lane = tid & 63;
  int lg = lane >> 4, lc = lane & 15;
  const unsigned short* qh = P.qb + (size_t)head * MPAD * 64;
  const unsigned short* kh = P.kb + (size_t)head * MPAD * 64;
  const unsigned short* vh = P.vT + (size_t)head * 64 * SPAD;

  short8 aq0 = *(const short8*)(qh + (size_t)(q0 + lc) * 64 + lg * 8);
  short8 aq1 = *(const short8*)(qh + (size_t)(q0 + lc) * 64 + 32 + lg * 8);

  float4_t sc[5];
  int st[5]; int nst = 0;
#pragma unroll
  for (int j = 0; j < 5; ++j) {
    int t = wave + j * 4;
    st[j] = (t < 17) ? t : 0;
    if (t < 17) nst = j + 1;
    sc[j] = (float4_t){0,0,0,0};
  }
#pragma unroll
  for (int j = 0; j < 5; ++j) {
    if (j < nst) {
      const unsigned short* kp = kh + (size_t)(st[j] * 16 + lc) * 64 + lg * 8;
      short8 b0 = *(const short8*)kp;
      short8 b1 = *(const short8*)(kp + 32);
      sc[j] = MFMAs(aq0, b0, sc[j]);
      sc[j] = MFMAs(aq1, b1, sc[j]);
    }
  }
  float mx[4] = {-1e30f, -1e30f, -1e30f, -1e30f};
#pragma unroll
  for (int j = 0; j < 5; ++j) {
    if (j < nst) {
      int sg = st[j] * 16 + lc;
#pragma unroll
      for (int r = 0; r < 4; ++r) {
        float vv = sc[j][r] * 0.125f;
        if (sg >= 257) vv = -1e30f;
        else if (q0 + lg * 4 + r == 0 && sg >= 1) vv += P.pbv[sg - 1];
        sc[j][r] = vv;
        mx[r] = fmaxf(mx[r], vv);
      }
    }
  }
#pragma unroll
  for (int r = 0; r < 4; ++r) {
    mx[r] = fmaxf(mx[r], __shfl_xor(mx[r], 1, 64));
    mx[r] = fmaxf(mx[r], __shfl_xor(mx[r], 2, 64));
    mx[r] = fmaxf(mx[r], __shfl_xor(mx[r], 4, 64));
    mx[r] = fmaxf(mx[r], __shfl_xor(mx[r], 8, 64));
  }
  if (lc == 0) {
#pragma unroll
    for (int r = 0; r < 4; ++r) smax[wave * 16 + lg * 4 + r] = mx[r];
  }
  __syncthreads();
  float fm[4], den[4] = {0, 0, 0, 0};
#pragma unroll
  for (int r = 0; r < 4; ++r) {
    int qq = lg * 4 + r;
    fm[r] = fmaxf(fmaxf(smax[qq], smax[16 + qq]), fmaxf(smax[32 + qq], smax[48 + qq]));
  }
#pragma unroll
  for (int j = 0; j < 5; ++j) {
    if (j < nst) {
#pragma unroll
      for (int r = 0; r < 4; ++r) {
        float pe = __expf(sc[j][r] - fm[r]);
        sc[j][r] = pe;
        den[r] += pe;
      }
    }
  }
#pragma unroll
  for (int r = 0; r < 4; ++r) {
    den[r] += __shfl_xor(den[r], 1, 64);
    den[r] += __shfl_xor(den[r], 2, 64);
    den[r] += __shfl_xor(den[r], 4, 64);
    den[r] += __shfl_xor(den[r], 8, 64);
  }
  if (lc == 0) {
#pragma unroll
    for (int r = 0; r < 4; ++r) sden[wave * 16 + lg * 4 + r] = den[r];
  }
  Pl[(tid >> 4) * SPAD + 272 + (tid & 15)] = 0;
#pragma unroll
  for (int j = 0; j < 5; ++j) {
    if (j < nst) {
#pragma unroll
      for (int r = 0; r < 4; ++r) Pl[(lg * 4 + r) * SPAD + st[j] * 16 + lc] = f2bf(sc[j][r]);
    }
  }
  __syncthreads();
  float denf[4];
#pragma unroll
  for (int r = 0; r < 4; ++r) {
    int qq = lg * 4 + r;
    denf[r] = sden[qq] + sden[16 + qq] + sden[32 + qq] + sden[48 + qq];
  }
  int d0 = wave * 16;
  float4_t oa = {0, 0, 0, 0};
#pragma unroll
  for (int s9 = 0; s9 < 9; ++s9) {
    short8 pa = *(const short8*)(Pl + lc * SPAD + s9 * 32 + lg * 8);
    short8 bv = *(const short8*)(vh + (size_t)(d0 + lc) * SPAD + s9 * 32 + lg * 8);
    oa = MFMAs(pa, bv, oa);
  }
#pragma unroll
  for (int r = 0; r < 4; ++r) {
    int qg = q0 + lg * 4 + r;
    P.ob[(size_t)qg * E_DIM + head * 64 + d0 + lc] = f2bf(oa[r] / denf[r]);
  }
}

// ---------------------------------------------------------------------------
// ROI phase
// ---------------------------------------------------------------------------
__device__ void phase_roi(const MegaParams& P, char* smem, int v, int tid) {
  int c0 = tid * 4;
  if (v == 0) {
    *(float4_t*)(P.out + c0) = *(const float4_t*)(P.x + c0);
  } else {
    float* mi = (float*)smem;
    mi[tid] = P.Mi[(v - 1) * 256 + tid];
    __syncthreads();
    float4_t acc = {0, 0, 0, 0};
    for (int p = 0; p < 256; ++p) {
      float4_t xv = *(const float4_t*)(P.x + (size_t)(1 + p) * E_DIM + c0);
      acc += mi[p] * xv;
    }
    *(float4_t*)(P.out + (size_t)v * E_DIM + c0) = acc;
  }
}

// ---------------------------------------------------------------------------
// The persistent megakernel
// ---------------------------------------------------------------------------
__global__ __launch_bounds__(256, 2) void vit_mega(MegaParams P) {
  __shared__ __align__(16) char smem[16384];
  const int bid = blockIdx.x, tid = threadIdx.x;
  unsigned* bar = P.bar;

  phase_prep(P, bid * 256 + tid);
  gsync(bar);

  if (bid == NB - 1) phase_pbcls(P, smem, tid);
  else if (bid < 64) phase_conv(P, bid, tid);
  gsync(bar);

  for (int m = bid; m < 257; m += NB)
    phase_ln(P.x, nullptr, 0, nullptr, P.ln1_s, P.ln1_b, P.h, m, tid, smem);
  gsync(bar);

  for (int l = 0; l < LAYERS; ++l) {
    const size_t o2 = (size_t)l * E_DIM * E_DIM;
    const size_t o1 = (size_t)l * E_DIM;
    const size_t of1 = (size_t)l * E_DIM * FF_DIM;
    const size_t ofb = (size_t)l * FF_DIM;

    // QKV: 192 items (nt 0..191 -> q/k/vT), K=1024 (8 BK-tiles)
    phase_gemm<1024, 0, 8>(smem, bid, 192, 192, P.h, E_DIM,
                           P.wq + o2, P.wk + o2, P.wv + o2,
                           P.bq + o1, P.bk + o1, P.bv + o1,
                           P.qb, P.kb, P.vT, nullptr, nullptr, tid);
    gsync(bar);

    for (int v = bid; v < 272; v += NB) phase_attn(P, smem, v, tid);
    gsync(bar);

    // O-proj: 256 items = 64 nt x KS4 (chunk 256 = 2 BK-tiles) -> partials
    phase_gemm<1024, 2, 2>(smem, bid, 256, 64, P.ob, E_DIM,
                           P.wo + o2, nullptr, nullptr, nullptr, nullptr, nullptr,
                           nullptr, nullptr, nullptr, nullptr, P.part, tid);
    gsync(bar);

    for (int m = bid; m < 257; m += NB)
      phase_ln(P.x, P.part, 4, P.bo + o1, P.ln2_s + o1, P.ln2_b + o1, P.h, m, tid, smem);
    gsync(bar);

    // FF1: 256 items = 256 nt, K=1024 (8 BK-tiles); fused bias+quickgelu
    phase_gemm<4096, 1, 8>(smem, bid, 256, 256, P.h, E_DIM,
                           P.w1 + of1, nullptr, nullptr, P.b1 + ofb, nullptr, nullptr,
                           nullptr, nullptr, nullptr, P.mb, nullptr, tid);
    gsync(bar);

    // FF2: 256 items = 64 nt x KS4 (chunk 1024 = 8 BK-tiles) -> partials
    phase_gemm<1024, 2, 8>(smem, bid, 256, 64, P.mb, FF_DIM,
                           P.w2 + of1, nullptr, nullptr, nullptr, nullptr, nullptr,
                           nullptr, nullptr, nullptr, nullptr, P.part, tid);
    gsync(bar);

    const float* nls = (l < LAYERS - 1) ? (P.ln1_s + (size_t)(l + 1) * E_DIM) : P.ln1_s;
    const float* nlb = (l < LAYERS - 1) ? (P.ln1_b + (size_t)(l + 1) * E_DIM) : P.ln1_b;
    for (int m = bid; m < 257; m += NB)
      phase_ln(P.x, P.part, 4, P.b2 + o1, nls, nlb, P.h, m, tid, smem);
    gsync(bar);
  }

  for (int v = bid; v < 33; v += NB) phase_roi(P, smem, v, tid);
}

// ---------------------------------------------------------------------------
extern "C" void kernel_launch(void* const* d_in, const int* in_sizes, int n_in,
                              void* d_out, int out_size, void* d_ws, size_t ws_size,
                              hipStream_t stream) {
  char* base = (char*)d_ws;
  auto carve = [&](size_t bytes) {
    char* r = base;
    base += (bytes + 255) & ~(size_t)255;
    return r;
  };
  unsigned* bar       = (unsigned*)carve(256);
  float* x            = (float*)carve((size_t)257 * E_DIM * 4);
  unsigned short* h   = (unsigned short*)carve((size_t)MPAD * E_DIM * 2);
  unsigned short* qb  = (unsigned short*)carve((size_t)16 * MPAD * 64 * 2);
  unsigned short* kbf = (unsigned short*)carve((size_t)16 * MPAD * 64 * 2);
  unsigned short* vTb = (unsigned short*)carve((size_t)16 * 64 * SPAD * 2);
  unsigned short* ob  = (unsigned short*)carve((size_t)MPAD * E_DIM * 2);
  unsigned short* mb  = (unsigned short*)carve((size_t)MPAD * FF_DIM * 2);
  float* part         = (float*)carve((size_t)4 * MPAD * E_DIM * 4);
  float* pbv          = (float*)carve(256 * 4);
  float* Mi           = (float*)carve(32 * 256 * 4);
  unsigned short* Pm  = (unsigned short*)carve((size_t)256 * KCP * 2);
  unsigned short* Wp  = (unsigned short*)carve((size_t)1024 * KCP * 2);

  MegaParams mp;
  mp.frame  = (const float*)d_in[0];
  mp.bboxes = (const float*)d_in[1];
  mp.conv_w = (const float*)d_in[2];
  mp.cls_emb= (const float*)d_in[3];
  mp.ln1_s  = (const float*)d_in[4];
  mp.ln1_b  = (const float*)d_in[5];
  mp.wq = (const float*)d_in[6];  mp.bq = (const float*)d_in[7];
  mp.wk = (const float*)d_in[8];  mp.bk = (const float*)d_in[9];
  mp.wv = (const float*)d_in[10]; mp.bv = (const float*)d_in[11];
  mp.wo = (const float*)d_in[12]; mp.bo = (const float*)d_in[13];
  mp.ln2_s = (const float*)d_in[14]; mp.ln2_b = (const float*)d_in[15];
  mp.w1 = (const float*)d_in[16]; mp.b1 = (const float*)d_in[17];
  mp.w2 = (const float*)d_in[18]; mp.b2 = (const float*)d_in[19];
  mp.x = x; mp.h = h; mp.qb = qb; mp.kb = kbf; mp.vT = vTb; mp.ob = ob; mp.mb = mb;
  mp.part = part; mp.pbv = pbv; mp.Mi = Mi; mp.Pm = Pm; mp.Wp = Wp;
  mp.out = (float*)d_out; mp.bar = bar;

  hipMemsetAsync(bar, 0, 256, stream);
  vit_mega<<<NB, 256, 0, stream>>>(mp);
}

// Round 6
// 12019.773 us; speedup vs baseline: 1.6835x; 1.6835x over previous
//
#include <hip/hip_runtime.h>
#include <hip/hip_bf16.h>
#include <math.h>

#define E_DIM 1024
#define FF_DIM 4096
#define LAYERS 24
#define MPAD 320      // 20 * 16 token-row padding (rows 257..319 zero / ignored)
#define SPAD 288      // vT / P column padding (9 * 32)
#define KCP 608       // conv K (588) padded to 19*32
#define NB 256        // persistent grid blocks (1/CU, co-residency guaranteed)

typedef __attribute__((ext_vector_type(8))) short short8;
typedef __attribute__((ext_vector_type(8))) __bf16 bf16x8;
typedef __attribute__((ext_vector_type(4))) float float4_t;
typedef __attribute__((ext_vector_type(4))) unsigned short ushort4_t;

union ABu { short8 s; bf16x8 b; };
union BFU { __bf16 b; unsigned short u; };

__device__ __forceinline__ float4_t MFMAs(short8 a, short8 b, float4_t c) {
  ABu ua, ub; ua.s = a; ub.s = b;
  return __builtin_amdgcn_mfma_f32_16x16x32_bf16(ua.b, ub.b, c, 0, 0, 0);
}
__device__ __forceinline__ unsigned short f2bf(float f) {
  BFU x; x.b = (__bf16)f; return x.u;
}

struct MegaParams {
  const float *frame, *bboxes, *conv_w, *cls_emb;
  const float *ln1_s, *ln1_b;
  const float *wq, *bq, *wk, *bk, *wv, *bv, *wo, *bo;
  const float *ln2_s, *ln2_b, *w1, *b1, *w2, *b2;
  float* x;
  unsigned short *h, *qb, *kb, *vT, *ob, *mb;
  float *part, *pbv, *Mi;
  unsigned short *Pm, *Wp;
  float* out;
  unsigned* bar;
};

// ---------------------------------------------------------------------------
// Device-wide barrier, v2. Monotone counters (no reset race), 16-leaf arrival
// tree (leaf = bid&15, 128B apart), RELAXED agent atomics in the spin loop
// (agent atomics bypass non-coherent L2 -> progress; no per-poll cache inv).
// Exactly one release fence before arrive, one acquire fence after exit.
// bar[ (bid&15)*32 ] leaves; bar[512] root; bar[544] generation.
// ---------------------------------------------------------------------------
__device__ __forceinline__ void gsync(unsigned* bar, int bid) {
  __threadfence();   // release: drain stores, write back to coherence point
  __syncthreads();
  if (threadIdx.x == 0) {
    unsigned g = __hip_atomic_load(bar + 544, __ATOMIC_RELAXED, __HIP_MEMORY_SCOPE_AGENT);
    unsigned a = __hip_atomic_fetch_add(bar + (bid & 15) * 32, 1u,
                                        __ATOMIC_RELAXED, __HIP_MEMORY_SCOPE_AGENT);
    if ((a & 15u) == 15u) {   // 16 blocks per leaf
      unsigned r = __hip_atomic_fetch_add(bar + 512, 1u,
                                          __ATOMIC_RELAXED, __HIP_MEMORY_SCOPE_AGENT);
      if ((r & 15u) == 15u)   // 16 leaves
        __hip_atomic_fetch_add(bar + 544, 1u, __ATOMIC_RELAXED, __HIP_MEMORY_SCOPE_AGENT);
    }
    while (__hip_atomic_load(bar + 544, __ATOMIC_RELAXED, __HIP_MEMORY_SCOPE_AGENT) == g)
      __builtin_amdgcn_s_sleep(4);
  }
  __syncthreads();
  __threadfence();   // acquire: invalidate caches once, post-barrier reads fresh
}

// ---------------------------------------------------------------------------
// Phase: prep (im2col, conv-weight repack, pad zeroing) — grid-stride
// ---------------------------------------------------------------------------
__device__ void phase_prep(const MegaParams& P, int gtid) {
  for (int i = gtid; i < 256 * KCP; i += NB * 256) {
    int b = i / KCP, kk = i - b * KCP;
    unsigned short us = 0;
    if (kk < 588) {
      int c = kk / 196, rem = kk % 196;
      int pr = b >> 4, pc = b & 15;
      int ii = rem / 14, jj = rem % 14;
      us = f2bf(P.frame[c * 224 * 224 + (pr * 14 + ii) * 224 + (pc * 14 + jj)]);
    }
    P.Pm[i] = us;
  }
  for (int i = gtid; i < 1024 * KCP; i += NB * 256) {
    int n = i / KCP, kk = i - n * KCP;
    P.Wp[i] = (kk < 588) ? f2bf(P.conv_w[n * 588 + kk]) : (unsigned short)0;
  }
  const int NH = (MPAD - 257) * E_DIM;
  const int NO = (MPAD - 272) * E_DIM;
  const int NV = 16 * 64 * (SPAD - 272);
  for (int i = gtid; i < NH + NO + NV; i += NB * 256) {
    if (i < NH) P.h[257 * E_DIM + i] = 0;
    else if (i < NH + NO) P.ob[272 * E_DIM + (i - NH)] = 0;
    else {
      int k = i - NH - NO;
      P.vT[(size_t)(k >> 4) * SPAD + 272 + (k & 15)] = 0;
    }
  }
}

// ---------------------------------------------------------------------------
// Phase: pb_cls (one block)
// ---------------------------------------------------------------------------
__device__ void phase_pbcls(const MegaParams& P, char* smem, int tid) {
  float* sb = (float*)smem;
  float* red = sb + 128;
  if (tid < 128) sb[tid] = P.bboxes[tid];
  __syncthreads();
  int p = tid;
  float px1 = (float)((p & 15) * 14), py1 = (float)((p >> 4) * 14);
  float px2 = px1 + 14.f, py2 = py1 + 14.f;
  float s = 0.f;
  for (int r = 0; r < 32; ++r) {
    float bx1 = sb[r * 4 + 0], by1 = sb[r * 4 + 1], bx2 = sb[r * 4 + 2], by2 = sb[r * 4 + 3];
    float iw = fmaxf(fminf(bx2, px2) - fmaxf(bx1, px1), 0.f);
    float ih = fmaxf(fminf(by2, py2) - fmaxf(by1, py1), 0.f);
    float ov = iw * ih * (1.f / 196.f);
    P.Mi[r * 256 + p] = ov;
    s += ov;
  }
  red[tid] = s;
  __syncthreads();
  for (int off = 128; off > 0; off >>= 1) {
    if (tid < off) red[tid] = fmaxf(red[tid], red[tid + off]);
    __syncthreads();
  }
  P.pbv[p] = s / (red[0] + 1e-6f);
  for (int j = 0; j < 4; ++j) P.x[tid * 4 + j] = P.cls_emb[tid * 4 + j];
}

// ---------------------------------------------------------------------------
// Phase: conv GEMM (blocks 0..63)
// ---------------------------------------------------------------------------
__device__ void phase_conv(const MegaParams& P, int vb, int tid) {
  int n0 = vb * 16;
  int wave = tid >> 6, lane = tid & 63;
  int lg = lane >> 4, lc = lane & 15;
  float4_t acc[4] = {{0,0,0,0},{0,0,0,0},{0,0,0,0},{0,0,0,0}};
  const unsigned short* bp = P.Wp + (size_t)(n0 + lc) * KCP + lg * 8;
  const unsigned short* apt[4];
#pragma unroll
  for (int t = 0; t < 4; ++t) apt[t] = P.Pm + (size_t)((wave + t * 4) * 16 + lc) * KCP + lg * 8;
  for (int s = 0; s < 19; ++s) {
    short8 bf = *(const short8*)bp; bp += 32;
#pragma unroll
    for (int t = 0; t < 4; ++t) {
      short8 af = *(const short8*)apt[t]; apt[t] += 32;
      acc[t] = MFMAs(af, bf, acc[t]);
    }
  }
#pragma unroll
  for (int t = 0; t < 4; ++t) {
    int mbase = (wave + t * 4) * 16 + lg * 4;
#pragma unroll
    for (int r = 0; r < 4; ++r)
      P.x[(size_t)(1 + mbase + r) * E_DIM + n0 + lc] = fmaxf(acc[t][r], 0.f);
  }
}

// ---------------------------------------------------------------------------
// Phase: residual-reduce + LayerNorm for one token row m
// ---------------------------------------------------------------------------
__device__ void phase_ln(float* x, const float* part, int nparts, const float* rbias,
                         const float* lns, const float* lnb, unsigned short* hout,
                         int m, int tid, char* smem) {
  float* red = (float*)smem;
  int c0 = tid * 4;
  float4_t v = *(const float4_t*)(x + (size_t)m * E_DIM + c0);
  if (rbias) v += *(const float4_t*)(rbias + c0);
  for (int s = 0; s < nparts; ++s)
    v += *(const float4_t*)(part + ((size_t)s * MPAD + m) * E_DIM + c0);
  if (nparts > 0) *(float4_t*)(x + (size_t)m * E_DIM + c0) = v;
  float s1 = v[0] + v[1] + v[2] + v[3];
  float s2 = v[0] * v[0] + v[1] * v[1] + v[2] * v[2] + v[3] * v[3];
#pragma unroll
  for (int off = 1; off < 64; off <<= 1) {
    s1 += __shfl_xor(s1, off, 64);
    s2 += __shfl_xor(s2, off, 64);
  }
  int wave = tid >> 6, lane = tid & 63;
  if (lane == 0) { red[wave * 2] = s1; red[wave * 2 + 1] = s2; }
  __syncthreads();
  s1 = red[0] + red[2] + red[4] + red[6];
  s2 = red[1] + red[3] + red[5] + red[7];
  float mean = s1 * (1.f / 1024.f);
  float var = s2 * (1.f / 1024.f) - mean * mean;
  float rstd = rsqrtf(var + 1e-5f);
  float4_t ls = *(const float4_t*)(lns + c0);
  float4_t lb = *(const float4_t*)(lnb + c0);
  ushort4_t hv;
#pragma unroll
  for (int r = 0; r < 4; ++r) hv[r] = f2bf((v[r] - mean) * rstd * ls[r] + lb[r]);
  *(ushort4_t*)(hout + (size_t)m * E_DIM + c0) = hv;
  __syncthreads();
}

// ---------------------------------------------------------------------------
// GEMM phase: C[m][n] = A[m][:] (bf16) . W[:][n] (fp32->bf16)
// item = (nt, ks): 16 N-cols x ALL 320 M-rows x K-chunk (NK x BK128).
// W-tile staged TRANSPOSED as bf16 in LDS [2][16 cols][136 rows]:
//  - stage: f32->bf16 cvt once, scattered b16 writes (once per tile)
//  - read: one conflict-free ds_read_b128 per substep per lane
// Double-buffered, 2-tile-deep register prefetch.
// ---------------------------------------------------------------------------
template <int NTOT, int EPI, int NK>
__device__ void phase_gemm(char* smem, int vb, int NITEMS, int NT,
                           const unsigned short* A, int lda,
                           const float* Wa, const float* Wb2, const float* Wc,
                           const float* ba, const float* bb, const float* bc,
                           unsigned short* oq, unsigned short* okk,
                           unsigned short* ovT, unsigned short* om,
                           float* opart, int tid) {
  if (vb >= NITEMS) return;
  unsigned short* Wt = (unsigned short*)smem;   // [2][16][136] bf16
  int nt = vb % NT, ks = vb / NT;
  int wave = tid >> 6, lane = tid & 63;
  int lg = lane >> 4, lc = lane & 15;

  const float* W; const float* bias; int ncol;
  if (EPI == 0) {
    int sel = nt >> 6; ncol = (nt & 63) << 4;
    W = (sel == 0) ? Wa : ((sel == 1) ? Wb2 : Wc);
    bias = (sel == 0) ? ba : ((sel == 1) ? bb : bc);
  } else {
    ncol = nt << 4; W = Wa; bias = ba;
  }

  const int kb0 = ks * (NK * 128);
  const int srow = wave * 32 + (lane >> 2);
  const int scol = (lane & 3) * 4;
  const float* wsrc = W + (size_t)(kb0 + srow) * NTOT + ncol + scol;

  const unsigned short* ap[5];
#pragma unroll
  for (int j = 0; j < 5; ++j)
    ap[j] = A + (size_t)((wave + 4 * j) * 16 + lc) * lda + kb0 + lg * 8;

  float4_t acc[5] = {{0,0,0,0},{0,0,0,0},{0,0,0,0},{0,0,0,0},{0,0,0,0}};
  float4_t p0, p1, p2, p3;

  // stage tile 0 (buf 0)
  p0 = *(const float4_t*)wsrc;
  p1 = *(const float4_t*)(wsrc + (size_t)16 * NTOT);
  wsrc += (size_t)128 * NTOT;
#pragma unroll
  for (int j = 0; j < 4; ++j) {
    Wt[(scol + j) * 136 + srow] = f2bf(p0[j]);
    Wt[(scol + j) * 136 + srow + 16] = f2bf(p1[j]);
  }
  // prefetch tiles 1, 2 into registers
  if (NK > 1) {
    p0 = *(const float4_t*)wsrc;
    p1 = *(const float4_t*)(wsrc + (size_t)16 * NTOT);
    wsrc += (size_t)128 * NTOT;
  }
  if (NK > 2) {
    p2 = *(const float4_t*)wsrc;
    p3 = *(const float4_t*)(wsrc + (size_t)16 * NTOT);
    wsrc += (size_t)128 * NTOT;
  }

  for (int t = 0; t < NK; ++t) {
    __syncthreads();   // prior reads of buf (t+1)&1 done; tile t writes visible
    if (t + 1 < NK) {
      unsigned short* base = Wt + ((t + 1) & 1) * 2176;
#pragma unroll
      for (int j = 0; j < 4; ++j) {
        base[(scol + j) * 136 + srow] = f2bf(p0[j]);
        base[(scol + j) * 136 + srow + 16] = f2bf(p1[j]);
      }
      p0 = p2; p1 = p3;
      if (t + 3 < NK) {
        p2 = *(const float4_t*)wsrc;
        p3 = *(const float4_t*)(wsrc + (size_t)16 * NTOT);
        wsrc += (size_t)128 * NTOT;
      }
    }
    const unsigned short* WB = Wt + (t & 1) * 2176 + lc * 136;
#pragma unroll
    for (int s = 0; s < 4; ++s) {
      short8 wf = *(const short8*)(WB + s * 32 + lg * 8);
#pragma unroll
      for (int j = 0; j < 5; ++j) {
        short8 a = *(const short8*)ap[j]; ap[j] += 32;
        acc[j] = MFMAs(wf, a, acc[j]);
      }
    }
  }

  float4_t bvv = {0,0,0,0};
  if (bias) bvv = *(const float4_t*)(bias + ncol + lg * 4);

  if (EPI == 0) {
    int sel = nt >> 6;
    int head = ncol >> 6;
    int dbase = (ncol & 63) + lg * 4;
#pragma unroll
    for (int j = 0; j < 5; ++j) {
      int tile = wave + 4 * j;
      int m = tile * 16 + lc;
      if (sel < 2) {
        unsigned short* dst = (sel == 0 ? oq : okk) + ((size_t)(head * MPAD + m)) * 64 + dbase;
        ushort4_t hv;
#pragma unroll
        for (int r = 0; r < 4; ++r) hv[r] = f2bf(acc[j][r] + bvv[r]);
        *(ushort4_t*)dst = hv;
      } else if (tile < 17) {
#pragma unroll
        for (int r = 0; r < 4; ++r)
          ovT[(size_t)(head * 64 + dbase + r) * SPAD + m] = f2bf(acc[j][r] + bvv[r]);
      }
    }
  } else if (EPI == 1) {
#pragma unroll
    for (int j = 0; j < 5; ++j) {
      int m = (wave + 4 * j) * 16 + lc;
      ushort4_t hv;
#pragma unroll
      for (int r = 0; r < 4; ++r) {
        float v = acc[j][r] + bvv[r];
        v = v / (1.f + __expf(-1.702f * v));
        hv[r] = f2bf(v);
      }
      *(ushort4_t*)(om + (size_t)m * FF_DIM + ncol + lg * 4) = hv;
    }
  } else {
#pragma unroll
    for (int j = 0; j < 5; ++j) {
      int m = (wave + 4 * j) * 16 + lc;
      *(float4_t*)(opart + ((size_t)ks * MPAD + m) * E_DIM + ncol + lg * 4) = acc[j];
    }
  }
}

// ---------------------------------------------------------------------------
// Attention phase: item v = head*17 + qtile
// ---------------------------------------------------------------------------
__device__ void phase_attn(const MegaParams& P, char* smem, int v, int tid) {
  float* smax = (float*)smem;
  float* sden = smax + 64;
  unsigned short* Pl = (unsigned short*)(sden + 64);  // [16][288]
  int head = v / 17, qt = v % 17;
  int q0 = qt * 16;
  int wave = tid >> 6, lane = tid & 63;
  int lg = lane >> 4, lc = lane & 15;
  const unsigned short* qh = P.qb + (size_t)head * MPAD * 64;
  const unsigned short* kh = P.kb + (size_t)head * MPAD * 64;
  const unsigned short* vh = P.vT + (size_t)head * 64 * SPAD;

  short8 aq0 = *(const short8*)(qh + (size_t)(q0 + lc) * 64 + lg * 8);
  short8 aq1 = *(const short8*)(qh + (size_t)(q0 + lc) * 64 + 32 + lg * 8);

  float4_t sc[5];
  int st[5]; int nst = 0;
#pragma unroll
  for (int j = 0; j < 5; ++j) {
    int t = wave + j * 4;
    st[j] = (t < 17) ? t : 0;
    if (t < 17) nst = j + 1;
    sc[j] = (float4_t){0,0,0,0};
  }
#pragma unroll
  for (int j = 0; j < 5; ++j) {
    if (j < nst) {
      const unsigned short* kp = kh + (size_t)(st[j] * 16 + lc) * 64 + lg * 8;
      short8 b0 = *(const short8*)kp;
      short8 b1 = *(const short8*)(kp + 32);
      sc[j] = MFMAs(aq0, b0, sc[j]);
      sc[j] = MFMAs(aq1, b1, sc[j]);
    }
  }
  float mx[4] = {-1e30f, -1e30f, -1e30f, -1e30f};
#pragma unroll
  for (int j = 0; j < 5; ++j) {
    if (j < nst) {
      int sg = st[j] * 16 + lc;
#pragma unroll
      for (int r = 0; r < 4; ++r) {
        float vv = sc[j][r] * 0.125f;
        if (sg >= 257) vv = -1e30f;
        else if (q0 + lg * 4 + r == 0 && sg >= 1) vv += P.pbv[sg - 1];
        sc[j][r] = vv;
        mx[r] = fmaxf(mx[r], vv);
      }
    }
  }
#pragma unroll
  for (int r = 0; r < 4; ++r) {
    mx[r] = fmaxf(mx[r], __shfl_xor(mx[r], 1, 64));
    mx[r] = fmaxf(mx[r], __shfl_xor(mx[r], 2, 64));
    mx[r] = fmaxf(mx[r], __shfl_xor(mx[r], 4, 64));
    mx[r] = fmaxf(mx[r], __shfl_xor(mx[r], 8, 64));
  }
  if (lc == 0) {
#pragma unroll
    for (int r = 0; r < 4; ++r) smax[wave * 16 + lg * 4 + r] = mx[r];
  }
  __syncthreads();
  float fm[4], den[4] = {0, 0, 0, 0};
#pragma unroll
  for (int r = 0; r < 4; ++r) {
    int qq = lg * 4 + r;
    fm[r] = fmaxf(fmaxf(smax[qq], smax[16 + qq]), fmaxf(smax[32 + qq], smax[48 + qq]));
  }
#pragma unroll
  for (int j = 0; j < 5; ++j) {
    if (j < nst) {
#pragma unroll
      for (int r = 0; r < 4; ++r) {
        float pe = __expf(sc[j][r] - fm[r]);
        sc[j][r] = pe;
        den[r] += pe;
      }
    }
  }
#pragma unroll
  for (int r = 0; r < 4; ++r) {
    den[r] += __shfl_xor(den[r], 1, 64);
    den[r] += __shfl_xor(den[r], 2, 64);
    den[r] += __shfl_xor(den[r], 4, 64);
    den[r] += __shfl_xor(den[r], 8, 64);
  }
  if (lc == 0) {
#pragma unroll
    for (int r = 0; r < 4; ++r) sden[wave * 16 + lg * 4 + r] = den[r];
  }
  Pl[(tid >> 4) * SPAD + 272 + (tid & 15)] = 0;
#pragma unroll
  for (int j = 0; j < 5; ++j) {
    if (j < nst) {
#pragma unroll
      for (int r = 0; r < 4; ++r) Pl[(lg * 4 + r) * SPAD + st[j] * 16 + lc] = f2bf(sc[j][r]);
    }
  }
  __syncthreads();
  float denf[4];
#pragma unroll
  for (int r = 0; r < 4; ++r) {
    int qq = lg * 4 + r;
    denf[r] = sden[qq] + sden[16 + qq] + sden[32 + qq] + sden[48 + qq];
  }
  int d0 = wave * 16;
  float4_t oa = {0, 0, 0, 0};
#pragma unroll
  for (int s9 = 0; s9 < 9; ++s9) {
    short8 pa = *(const short8*)(Pl + lc * SPAD + s9 * 32 + lg * 8);
    short8 bv = *(const short8*)(vh + (size_t)(d0 + lc) * SPAD + s9 * 32 + lg * 8);
    oa = MFMAs(pa, bv, oa);
  }
#pragma unroll
  for (int r = 0; r < 4; ++r) {
    int qg = q0 + lg * 4 + r;
    P.ob[(size_t)qg * E_DIM + head * 64 + d0 + lc] = f2bf(oa[r] / denf[r]);
  }
  __syncthreads();   // safe smem reuse if this block runs a 2nd item
}

// ---------------------------------------------------------------------------
// ROI phase
// ---------------------------------------------------------------------------
__device__ void phase_roi(const MegaParams& P, char* smem, int v, int tid) {
  int c0 = tid * 4;
  if (v == 0) {
    *(float4_t*)(P.out + c0) = *(const float4_t*)(P.x + c0);
  } else {
    float* mi = (float*)smem;
    mi[tid] = P.Mi[(v - 1) * 256 + tid];
    __syncthreads();
    float4_t acc = {0, 0, 0, 0};
    for (int p = 0; p < 256; ++p) {
      float4_t xv = *(const float4_t*)(P.x + (size_t)(1 + p) * E_DIM + c0);
      acc += mi[p] * xv;
    }
    *(float4_t*)(P.out + (size_t)v * E_DIM + c0) = acc;
  }
}

// ---------------------------------------------------------------------------
// The persistent megakernel
// ---------------------------------------------------------------------------
__global__ __launch_bounds__(256, 2) void vit_mega(MegaParams P) {
  __shared__ __align__(16) char smem[12288];
  const int bid = blockIdx.x, tid = threadIdx.x;
  unsigned* bar = P.bar;

  phase_prep(P, bid * 256 + tid);
  gsync(bar, bid);

  if (bid == NB - 1) phase_pbcls(P, smem, tid);
  else if (bid < 64) phase_conv(P, bid, tid);
  gsync(bar, bid);

  for (int m = bid; m < 257; m += NB)
    phase_ln(P.x, nullptr, 0, nullptr, P.ln1_s, P.ln1_b, P.h, m, tid, smem);
  gsync(bar, bid);

  for (int l = 0; l < LAYERS; ++l) {
    const size_t o2 = (size_t)l * E_DIM * E_DIM;
    const size_t o1 = (size_t)l * E_DIM;
    const size_t of1 = (size_t)l * E_DIM * FF_DIM;
    const size_t ofb = (size_t)l * FF_DIM;

    // QKV: 192 items, K=1024 (8 BK-tiles)
    phase_gemm<1024, 0, 8>(smem, bid, 192, 192, P.h, E_DIM,
                           P.wq + o2, P.wk + o2, P.wv + o2,
                           P.bq + o1, P.bk + o1, P.bv + o1,
                           P.qb, P.kb, P.vT, nullptr, nullptr, tid);
    gsync(bar, bid);

    for (int v = bid; v < 272; v += NB) phase_attn(P, smem, v, tid);
    gsync(bar, bid);

    // O-proj: 256 items = 64 nt x KS4 (chunk 256 = 2 BK-tiles)
    phase_gemm<1024, 2, 2>(smem, bid, 256, 64, P.ob, E_DIM,
                           P.wo + o2, nullptr, nullptr, nullptr, nullptr, nullptr,
                           nullptr, nullptr, nullptr, nullptr, P.part, tid);
    gsync(bar, bid);

    for (int m = bid; m < 257; m += NB)
      phase_ln(P.x, P.part, 4, P.bo + o1, P.ln2_s + o1, P.ln2_b + o1, P.h, m, tid, smem);
    gsync(bar, bid);

    // FF1: 256 items = 256 nt, K=1024 (8 BK-tiles)
    phase_gemm<4096, 1, 8>(smem, bid, 256, 256, P.h, E_DIM,
                           P.w1 + of1, nullptr, nullptr, P.b1 + ofb, nullptr, nullptr,
                           nullptr, nullptr, nullptr, P.mb, nullptr, tid);
    gsync(bar, bid);

    // FF2: 256 items = 64 nt x KS4 (chunk 1024 = 8 BK-tiles)
    phase_gemm<1024, 2, 8>(smem, bid, 256, 64, P.mb, FF_DIM,
                           P.w2 + of1, nullptr, nullptr, nullptr, nullptr, nullptr,
                           nullptr, nullptr, nullptr, nullptr, P.part, tid);
    gsync(bar, bid);

    const float* nls = (l < LAYERS - 1) ? (P.ln1_s + (size_t)(l + 1) * E_DIM) : P.ln1_s;
    const float* nlb = (l < LAYERS - 1) ? (P.ln1_b + (size_t)(l + 1) * E_DIM) : P.ln1_b;
    for (int m = bid; m < 257; m += NB)
      phase_ln(P.x, P.part, 4, P.b2 + o1, nls, nlb, P.h, m, tid, smem);
    gsync(bar, bid);
  }

  for (int v = bid; v < 33; v += NB) phase_roi(P, smem, v, tid);
}

// ---------------------------------------------------------------------------
extern "C" void kernel_launch(void* const* d_in, const int* in_sizes, int n_in,
                              void* d_out, int out_size, void* d_ws, size_t ws_size,
                              hipStream_t stream) {
  char* base = (char*)d_ws;
  auto carve = [&](size_t bytes) {
    char* r = base;
    base += (bytes + 255) & ~(size_t)255;
    return r;
  };
  unsigned* bar       = (unsigned*)carve(4096);
  float* x            = (float*)carve((size_t)257 * E_DIM * 4);
  unsigned short* h   = (unsigned short*)carve((size_t)MPAD * E_DIM * 2);
  unsigned short* qb  = (unsigned short*)carve((size_t)16 * MPAD * 64 * 2);
  unsigned short* kbf = (unsigned short*)carve((size_t)16 * MPAD * 64 * 2);
  unsigned short* vTb = (unsigned short*)carve((size_t)16 * 64 * SPAD * 2);
  unsigned short* ob  = (unsigned short*)carve((size_t)MPAD * E_DIM * 2);
  unsigned short* mb  = (unsigned short*)carve((size_t)MPAD * FF_DIM * 2);
  float* part         = (float*)carve((size_t)4 * MPAD * E_DIM * 4);
  float* pbv          = (float*)carve(256 * 4);
  float* Mi           = (float*)carve(32 * 256 * 4);
  unsigned short* Pm  = (unsigned short*)carve((size_t)256 * KCP * 2);
  unsigned short* Wp  = (unsigned short*)carve((size_t)1024 * KCP * 2);

  MegaParams mp;
  mp.frame  = (const float*)d_in[0];
  mp.bboxes = (const float*)d_in[1];
  mp.conv_w = (const float*)d_in[2];
  mp.cls_emb= (const float*)d_in[3];
  mp.ln1_s  = (const float*)d_in[4];
  mp.ln1_b  = (const float*)d_in[5];
  mp.wq = (const float*)d_in[6];  mp.bq = (const float*)d_in[7];
  mp.wk = (const float*)d_in[8];  mp.bk = (const float*)d_in[9];
  mp.wv = (const float*)d_in[10]; mp.bv = (const float*)d_in[11];
  mp.wo = (const float*)d_in[12]; mp.bo = (const float*)d_in[13];
  mp.ln2_s = (const float*)d_in[14]; mp.ln2_b = (const float*)d_in[15];
  mp.w1 = (const float*)d_in[16]; mp.b1 = (const float*)d_in[17];
  mp.w2 = (const float*)d_in[18]; mp.b2 = (const float*)d_in[19];
  mp.x = x; mp.h = h; mp.qb = qb; mp.kb = kbf; mp.vT = vTb; mp.ob = ob; mp.mb = mb;
  mp.part = part; mp.pbv = pbv; mp.Mi = Mi; mp.Pm = Pm; mp.Wp = Wp;
  mp.out = (float*)d_out; mp.bar = bar;

  hipMemsetAsync(bar, 0, 4096, stream);
  vit_mega<<<NB, 256, 0, stream>>>(mp);
}

// Round 7
// 2387.542 us; speedup vs baseline: 8.4756x; 5.0344x over previous
//
#include <hip/hip_runtime.h>
#include <hip/hip_bf16.h>
#include <math.h>

#define E_DIM 1024
#define FF_DIM 4096
#define LAYERS 24
#define MPAD 320      // 20 * 16 token-row padding (rows 257..319 zero / ignored)
#define SPAD 288      // vT / P column padding (9 * 32)
#define KCP 608       // conv K (588) padded to 19*32

typedef __attribute__((ext_vector_type(8))) short short8;
typedef __attribute__((ext_vector_type(8))) __bf16 bf16x8;
typedef __attribute__((ext_vector_type(4))) float float4_t;
typedef __attribute__((ext_vector_type(4))) unsigned short ushort4_t;

union ABu { short8 s; bf16x8 b; };
union BFU { __bf16 b; unsigned short u; };

__device__ __forceinline__ float4_t MFMA(bf16x8 a, bf16x8 b, float4_t c) {
  return __builtin_amdgcn_mfma_f32_16x16x32_bf16(a, b, c, 0, 0, 0);
}
__device__ __forceinline__ float4_t MFMAs(short8 a, short8 b, float4_t c) {
  ABu ua, ub; ua.s = a; ub.s = b;
  return __builtin_amdgcn_mfma_f32_16x16x32_bf16(ua.b, ub.b, c, 0, 0, 0);
}
__device__ __forceinline__ unsigned short f2bf(float f) {
  BFU x; x.b = (__bf16)f; return x.u;
}

// async global->LDS: 16B per lane, LDS dest = wave-uniform base + lane*16
__device__ __forceinline__ void glds16(const float* src, float* dst) {
  __builtin_amdgcn_global_load_lds(
      (const __attribute__((address_space(1))) unsigned int*)src,
      (__attribute__((address_space(3))) unsigned int*)dst, 16, 0, 0);
}

// ---------------------------------------------------------------------------
// prep: im2col frame -> Pm ; conv_w -> Wp ; zero pads of h / ob / vT
// ---------------------------------------------------------------------------
__global__ void prep_kernel(const float* __restrict__ frame, const float* __restrict__ conv_w,
                            unsigned short* __restrict__ Pm, unsigned short* __restrict__ Wp,
                            unsigned short* __restrict__ h, unsigned short* __restrict__ ob,
                            unsigned short* __restrict__ vTb) {
  int b = blockIdx.x, tid = threadIdx.x;
  if (b < 256) {
    int pr = b >> 4, pc = b & 15;
    for (int kk = tid; kk < KCP; kk += 256) {
      unsigned short us = 0;
      if (kk < 588) {
        int c = kk / 196, rem = kk % 196;
        int i = rem / 14, j = rem % 14;
        us = f2bf(frame[c * 224 * 224 + (pr * 14 + i) * 224 + (pc * 14 + j)]);
      }
      Pm[b * KCP + kk] = us;
    }
  } else if (b < 1280) {
    int n = b - 256;
    for (int kk = tid; kk < KCP; kk += 256) {
      unsigned short us = (kk < 588) ? f2bf(conv_w[n * 588 + kk]) : (unsigned short)0;
      Wp[n * KCP + kk] = us;
    }
  } else {
    int idx = (b - 1280) * 256 + tid;
    const int NH = (MPAD - 257) * E_DIM;   // 64512
    const int NO = (MPAD - 272) * E_DIM;   // 49152
    const int NV = 16 * 64 * (SPAD - 272); // 16384
    if (idx < NH) {
      h[257 * E_DIM + idx] = 0;
    } else if (idx < NH + NO) {
      ob[272 * E_DIM + (idx - NH)] = 0;
    } else if (idx < NH + NO + NV) {
      int i = idx - NH - NO;
      vTb[(size_t)(i >> 4) * SPAD + 272 + (i & 15)] = 0;
    }
  }
}

// ---------------------------------------------------------------------------
// pb_cls
// ---------------------------------------------------------------------------
__global__ void pb_cls_kernel(const float* __restrict__ bboxes, const float* __restrict__ cls_emb,
                              float* __restrict__ pb, float* __restrict__ Mi, float* __restrict__ x) {
  __shared__ float sb[128];
  __shared__ float red[256];
  int tid = threadIdx.x;
  if (tid < 128) sb[tid] = bboxes[tid];
  __syncthreads();
  int p = tid;
  float px1 = (float)((p & 15) * 14), py1 = (float)((p >> 4) * 14);
  float px2 = px1 + 14.f, py2 = py1 + 14.f;
  float s = 0.f;
  for (int r = 0; r < 32; ++r) {
    float bx1 = sb[r * 4 + 0], by1 = sb[r * 4 + 1], bx2 = sb[r * 4 + 2], by2 = sb[r * 4 + 3];
    float iw = fmaxf(fminf(bx2, px2) - fmaxf(bx1, px1), 0.f);
    float ih = fmaxf(fminf(by2, py2) - fmaxf(by1, py1), 0.f);
    float ov = iw * ih * (1.f / 196.f);
    Mi[r * 256 + p] = ov;
    s += ov;
  }
  red[tid] = s;
  __syncthreads();
  for (int off = 128; off > 0; off >>= 1) {
    if (tid < off) red[tid] = fmaxf(red[tid], red[tid + off]);
    __syncthreads();
  }
  pb[p] = s / (red[0] + 1e-6f);
  for (int j = 0; j < 4; ++j) x[tid * 4 + j] = cls_emb[tid * 4 + j];
}

// ---------------------------------------------------------------------------
// conv GEMM
// ---------------------------------------------------------------------------
__global__ __launch_bounds__(256) void conv_gemm(const unsigned short* __restrict__ Pm,
                                                 const unsigned short* __restrict__ Wp,
                                                 float* __restrict__ x) {
  int n0 = blockIdx.x * 16;
  int tid = threadIdx.x, wave = tid >> 6, lane = tid & 63;
  int lg = lane >> 4, lc = lane & 15;
  float4_t acc[4] = {{0,0,0,0},{0,0,0,0},{0,0,0,0},{0,0,0,0}};
  const unsigned short* bp = Wp + (size_t)(n0 + lc) * KCP + lg * 8;
  const unsigned short* apt[4];
#pragma unroll
  for (int t = 0; t < 4; ++t) apt[t] = Pm + (size_t)((wave + t * 4) * 16 + lc) * KCP + lg * 8;
  for (int s = 0; s < 19; ++s) {
    short8 bf = *(const short8*)bp; bp += 32;
#pragma unroll
    for (int t = 0; t < 4; ++t) {
      short8 af = *(const short8*)apt[t]; apt[t] += 32;
      acc[t] = MFMAs(af, bf, acc[t]);
    }
  }
#pragma unroll
  for (int t = 0; t < 4; ++t) {
    int mbase = (wave + t * 4) * 16 + lg * 4;
#pragma unroll
    for (int r = 0; r < 4; ++r)
      x[(size_t)(1 + mbase + r) * E_DIM + n0 + lc] = fmaxf(acc[t][r], 0.f);
  }
}

// ---------------------------------------------------------------------------
// GEMM: C[m][n] = A[m][:] (bf16) . W[:][n] (fp32->bf16)
// Block = 16 N-cols x ALL 320 M-rows x K-chunk (NK tiles of 128 K-rows).
// Per tile: [hoist full A-tile to regs (oldest vmcnt)] -> [issue async
// global_load_lds for W tile t+1] -> [compute from LDS (lgkmcnt only)] ->
// [__syncthreads: single vmcnt(0) drain per tile].
// XCD pairing: blocks b and b+8 (same XCD) take adjacent 16-col slices so
// the two 64B halves of each 128B weight line are fetched once per XCD.
// ---------------------------------------------------------------------------
template <int NTOT, int EPI, int NK>
__global__ __launch_bounds__(256) void gemm_nk(
    const unsigned short* __restrict__ A, int lda,
    const float* __restrict__ Wa, const float* __restrict__ Wb2, const float* __restrict__ Wc,
    const float* __restrict__ ba, const float* __restrict__ bb, const float* __restrict__ bc,
    int NT,
    unsigned short* __restrict__ oq, unsigned short* __restrict__ okk,
    unsigned short* __restrict__ ovT, unsigned short* __restrict__ om,
    float* __restrict__ opart) {
  static_assert(NK >= 2, "double buffer needs >=2 K-tiles");
  __shared__ __align__(16) float Wt[2][128][16];
  int b = blockIdx.x;
  // XCD pairing: items 2p, 2p+1 -> blocks b, b+8 (same XCD). grid % 16 == 0.
  int item = (((b & 7) | ((b >> 4) << 3)) << 1) | ((b >> 3) & 1);
  int nt = item % NT, ks = item / NT;

  int tid = threadIdx.x, wave = tid >> 6, lane = tid & 63;
  int lg = lane >> 4, lc = lane & 15;

  const float* W; const float* bias; int ncol;
  if (EPI == 0) {
    int sel = nt >> 6; ncol = (nt & 63) << 4;
    W = (sel == 0) ? Wa : ((sel == 1) ? Wb2 : Wc);
    bias = (sel == 0) ? ba : ((sel == 1) ? bb : bc);
  } else {
    ncol = nt << 4; W = Wa; bias = ba;
  }

  const int kb0 = ks * (NK * 128);
  // stage source: lane covers row (lane>>2) of 16-row group, 16B of cols
  const float* wsrc0 = W + (size_t)(kb0 + (lane >> 2)) * NTOT + ncol + (lane & 3) * 4;

  const unsigned short* ap[5];
#pragma unroll
  for (int j = 0; j < 5; ++j)
    ap[j] = A + (size_t)((wave + 4 * j) * 16 + lc) * lda + kb0 + lg * 8;

  float4_t acc[5] = {{0,0,0,0},{0,0,0,0},{0,0,0,0},{0,0,0,0},{0,0,0,0}};

  // prologue: stage tile 0 into buf 0
  {
    const float* s0 = wsrc0;
#pragma unroll
    for (int i = 0; i < 2; ++i) {
      int rg = wave * 32 + i * 16;
      int off = __builtin_amdgcn_readfirstlane(rg * 16);
      glds16(s0 + (size_t)rg * NTOT, &Wt[0][0][0] + off);
    }
  }
  __syncthreads();   // vmcnt(0): tile 0 resident

  for (int t = 0; t < NK; ++t) {
    // 1) hoist full A-tile to registers (issued FIRST -> oldest vmcnt entries)
    short8 av[20];
#pragma unroll
    for (int s = 0; s < 4; ++s)
#pragma unroll
      for (int j = 0; j < 5; ++j)
        av[s * 5 + j] = *(const short8*)(ap[j] + s * 32);
#pragma unroll
    for (int j = 0; j < 5; ++j) ap[j] += 128;

    // 2) issue async stage of W tile t+1 (newest vmcnt entries)
    if (t + 1 < NK) {
      const float* sn = wsrc0 + (size_t)(t + 1) * 128 * NTOT;
      float* bufn = &Wt[(t + 1) & 1][0][0];
#pragma unroll
      for (int i = 0; i < 2; ++i) {
        int rg = wave * 32 + i * 16;
        int off = __builtin_amdgcn_readfirstlane(rg * 16);
        glds16(sn + (size_t)rg * NTOT, bufn + off);
      }
    }

    // 3) compute tile t from LDS (ds_read -> lgkmcnt; A waits don't touch glds)
    const float (*Wb_)[16] = Wt[t & 1];
#pragma unroll
    for (int s = 0; s < 4; ++s) {
      float wv[8];
#pragma unroll
      for (int i = 0; i < 8; ++i) wv[i] = Wb_[s * 32 + lg * 8 + i][lc];
      bf16x8 wf;
#pragma unroll
      for (int i = 0; i < 8; ++i) wf[i] = (__bf16)wv[i];
#pragma unroll
      for (int j = 0; j < 5; ++j) {
        ABu a; a.s = av[s * 5 + j];
        acc[j] = MFMA(wf, a.b, acc[j]);
      }
    }
    // 4) single drain point per tile: tile t+1 resident after this
    __syncthreads();
  }

  float4_t bvv = {0,0,0,0};
  if (bias) bvv = *(const float4_t*)(bias + ncol + lg * 4);

  if (EPI == 0) {
    int sel = nt >> 6;
    int head = ncol >> 6;
    int dbase = (ncol & 63) + lg * 4;
#pragma unroll
    for (int j = 0; j < 5; ++j) {
      int tile = wave + 4 * j;
      int m = tile * 16 + lc;
      if (sel < 2) {
        unsigned short* dst = (sel == 0 ? oq : okk) + ((size_t)(head * MPAD + m)) * 64 + dbase;
        ushort4_t hv;
#pragma unroll
        for (int r = 0; r < 4; ++r) hv[r] = f2bf(acc[j][r] + bvv[r]);
        *(ushort4_t*)dst = hv;
      } else if (tile < 17) {   // vT columns only exist for m < 272
#pragma unroll
        for (int r = 0; r < 4; ++r)
          ovT[(size_t)(head * 64 + dbase + r) * SPAD + m] = f2bf(acc[j][r] + bvv[r]);
      }
    }
  } else if (EPI == 1) {
#pragma unroll
    for (int j = 0; j < 5; ++j) {
      int m = (wave + 4 * j) * 16 + lc;
      ushort4_t hv;
#pragma unroll
      for (int r = 0; r < 4; ++r) {
        float v = acc[j][r] + bvv[r];
        v = v / (1.f + __expf(-1.702f * v));   // quick_gelu
        hv[r] = f2bf(v);
      }
      *(ushort4_t*)(om + (size_t)m * FF_DIM + ncol + lg * 4) = hv;
    }
  } else {
#pragma unroll
    for (int j = 0; j < 5; ++j) {
      int m = (wave + 4 * j) * 16 + lc;
      *(float4_t*)(opart + ((size_t)ks * MPAD + m) * E_DIM + ncol + lg * 4) = acc[j];
    }
  }
}

// ---------------------------------------------------------------------------
// Attention: grid = 16 heads * 17 q-tiles
// ---------------------------------------------------------------------------
__global__ __launch_bounds__(256) void attn_kernel(
    const unsigned short* __restrict__ qb, const unsigned short* __restrict__ kb,
    const unsigned short* __restrict__ vT, const float* __restrict__ pb,
    unsigned short* __restrict__ ob) {
  int head = blockIdx.x / 17, qt = blockIdx.x % 17;
  int q0 = qt * 16;
  int tid = threadIdx.x, wave = tid >> 6, lane = tid & 63;
  int lg = lane >> 4, lc = lane & 15;
  const unsigned short* qh = qb + (size_t)head * MPAD * 64;
  const unsigned short* kh = kb + (size_t)head * MPAD * 64;
  const unsigned short* vh = vT + (size_t)head * 64 * SPAD;

  short8 aq0 = *(const short8*)(qh + (size_t)(q0 + lc) * 64 + lg * 8);
  short8 aq1 = *(const short8*)(qh + (size_t)(q0 + lc) * 64 + 32 + lg * 8);

  float4_t sc[5];
  int st[5]; int nst = 0;
#pragma unroll
  for (int j = 0; j < 5; ++j) {
    int t = wave + j * 4;
    st[j] = (t < 17) ? t : 0;
    if (t < 17) nst = j + 1;
    sc[j] = (float4_t){0,0,0,0};
  }
#pragma unroll
  for (int j = 0; j < 5; ++j) {
    if (j < nst) {
      const unsigned short* kp = kh + (size_t)(st[j] * 16 + lc) * 64 + lg * 8;
      short8 b0 = *(const short8*)kp;
      short8 b1 = *(const short8*)(kp + 32);
      sc[j] = MFMAs(aq0, b0, sc[j]);
      sc[j] = MFMAs(aq1, b1, sc[j]);
    }
  }
  float mx[4] = {-1e30f, -1e30f, -1e30f, -1e30f};
#pragma unroll
  for (int j = 0; j < 5; ++j) {
    if (j < nst) {
      int sg = st[j] * 16 + lc;
#pragma unroll
      for (int r = 0; r < 4; ++r) {
        float v = sc[j][r] * 0.125f;
        if (sg >= 257) v = -1e30f;
        else if (q0 + lg * 4 + r == 0 && sg >= 1) v += pb[sg - 1];
        sc[j][r] = v;
        mx[r] = fmaxf(mx[r], v);
      }
    }
  }
#pragma unroll
  for (int r = 0; r < 4; ++r) {
    mx[r] = fmaxf(mx[r], __shfl_xor(mx[r], 1, 64));
    mx[r] = fmaxf(mx[r], __shfl_xor(mx[r], 2, 64));
    mx[r] = fmaxf(mx[r], __shfl_xor(mx[r], 4, 64));
    mx[r] = fmaxf(mx[r], __shfl_xor(mx[r], 8, 64));
  }
  __shared__ float smax[4][16];
  __shared__ float sden[4][16];
  __shared__ __align__(16) unsigned short P[16][SPAD];
  if (lc == 0) {
#pragma unroll
    for (int r = 0; r < 4; ++r) smax[wave][lg * 4 + r] = mx[r];
  }
  __syncthreads();
  float fm[4], den[4] = {0, 0, 0, 0};
#pragma unroll
  for (int r = 0; r < 4; ++r) {
    int qq = lg * 4 + r;
    fm[r] = fmaxf(fmaxf(smax[0][qq], smax[1][qq]), fmaxf(smax[2][qq], smax[3][qq]));
  }
#pragma unroll
  for (int j = 0; j < 5; ++j) {
    if (j < nst) {
#pragma unroll
      for (int r = 0; r < 4; ++r) {
        float pe = __expf(sc[j][r] - fm[r]);
        sc[j][r] = pe;
        den[r] += pe;
      }
    }
  }
#pragma unroll
  for (int r = 0; r < 4; ++r) {
    den[r] += __shfl_xor(den[r], 1, 64);
    den[r] += __shfl_xor(den[r], 2, 64);
    den[r] += __shfl_xor(den[r], 4, 64);
    den[r] += __shfl_xor(den[r], 8, 64);
  }
  if (lc == 0) {
#pragma unroll
    for (int r = 0; r < 4; ++r) sden[wave][lg * 4 + r] = den[r];
  }
  P[tid >> 4][272 + (tid & 15)] = 0;
#pragma unroll
  for (int j = 0; j < 5; ++j) {
    if (j < nst) {
#pragma unroll
      for (int r = 0; r < 4; ++r) P[lg * 4 + r][st[j] * 16 + lc] = f2bf(sc[j][r]);
    }
  }
  __syncthreads();
  float denf[4];
#pragma unroll
  for (int r = 0; r < 4; ++r) {
    int qq = lg * 4 + r;
    denf[r] = sden[0][qq] + sden[1][qq] + sden[2][qq] + sden[3][qq];
  }
  int d0 = wave * 16;
  float4_t oa = {0, 0, 0, 0};
#pragma unroll
  for (int s9 = 0; s9 < 9; ++s9) {
    short8 pa = *(const short8*)(&P[lc][s9 * 32 + lg * 8]);
    short8 bv = *(const short8*)(vh + (size_t)(d0 + lc) * SPAD + s9 * 32 + lg * 8);
    oa = MFMAs(pa, bv, oa);
  }
#pragma unroll
  for (int r = 0; r < 4; ++r) {
    int qg = q0 + lg * 4 + r;
    ob[(size_t)qg * E_DIM + head * 64 + d0 + lc] = f2bf(oa[r] / denf[r]);
  }
}

// ---------------------------------------------------------------------------
// reduce_ln
// ---------------------------------------------------------------------------
__global__ __launch_bounds__(256) void reduce_ln_kernel(
    float* __restrict__ x, const float* __restrict__ part, int nparts,
    const float* __restrict__ rbias,
    const float* __restrict__ lns, const float* __restrict__ lnb,
    unsigned short* __restrict__ hout) {
  int m = blockIdx.x, tid = threadIdx.x;
  int c0 = tid * 4;
  float4_t v = *(const float4_t*)(x + (size_t)m * E_DIM + c0);
  if (rbias) v += *(const float4_t*)(rbias + c0);
  for (int s = 0; s < nparts; ++s)
    v += *(const float4_t*)(part + ((size_t)s * MPAD + m) * E_DIM + c0);
  if (nparts > 0) *(float4_t*)(x + (size_t)m * E_DIM + c0) = v;
  float s1 = v[0] + v[1] + v[2] + v[3];
  float s2 = v[0] * v[0] + v[1] * v[1] + v[2] * v[2] + v[3] * v[3];
#pragma unroll
  for (int off = 1; off < 64; off <<= 1) {
    s1 += __shfl_xor(s1, off, 64);
    s2 += __shfl_xor(s2, off, 64);
  }
  __shared__ float red[8];
  int wave = tid >> 6, lane = tid & 63;
  if (lane == 0) { red[wave * 2] = s1; red[wave * 2 + 1] = s2; }
  __syncthreads();
  s1 = red[0] + red[2] + red[4] + red[6];
  s2 = red[1] + red[3] + red[5] + red[7];
  float mean = s1 * (1.f / 1024.f);
  float var = s2 * (1.f / 1024.f) - mean * mean;
  float rstd = rsqrtf(var + 1e-5f);
  float4_t ls = *(const float4_t*)(lns + c0);
  float4_t lb = *(const float4_t*)(lnb + c0);
  ushort4_t hv;
#pragma unroll
  for (int r = 0; r < 4; ++r) hv[r] = f2bf((v[r] - mean) * rstd * ls[r] + lb[r]);
  *(ushort4_t*)(hout + (size_t)m * E_DIM + c0) = hv;
}

// ---------------------------------------------------------------------------
// ROI pool
// ---------------------------------------------------------------------------
__global__ __launch_bounds__(256) void roi_kernel(const float* __restrict__ x,
                                                  const float* __restrict__ Mi,
                                                  float* __restrict__ out) {
  int b = blockIdx.x, tid = threadIdx.x;
  int c0 = tid * 4;
  if (b == 0) {
    *(float4_t*)(out + c0) = *(const float4_t*)(x + c0);
  } else {
    __shared__ float mi[256];
    mi[tid] = Mi[(b - 1) * 256 + tid];
    __syncthreads();
    float4_t acc = {0, 0, 0, 0};
    for (int p = 0; p < 256; ++p) {
      float4_t xv = *(const float4_t*)(x + (size_t)(1 + p) * E_DIM + c0);
      acc += mi[p] * xv;
    }
    *(float4_t*)(out + (size_t)b * E_DIM + c0) = acc;
  }
}

// ---------------------------------------------------------------------------
extern "C" void kernel_launch(void* const* d_in, const int* in_sizes, int n_in,
                              void* d_out, int out_size, void* d_ws, size_t ws_size,
                              hipStream_t stream) {
  const float* frame   = (const float*)d_in[0];
  const float* bboxes  = (const float*)d_in[1];
  const float* conv_w  = (const float*)d_in[2];
  const float* cls_emb = (const float*)d_in[3];
  const float* ln1_s   = (const float*)d_in[4];
  const float* ln1_b   = (const float*)d_in[5];
  const float* wq = (const float*)d_in[6];
  const float* bq = (const float*)d_in[7];
  const float* wk = (const float*)d_in[8];
  const float* bk = (const float*)d_in[9];
  const float* wv = (const float*)d_in[10];
  const float* bv = (const float*)d_in[11];
  const float* wo = (const float*)d_in[12];
  const float* bo = (const float*)d_in[13];
  const float* ln2_s = (const float*)d_in[14];
  const float* ln2_b = (const float*)d_in[15];
  const float* w1 = (const float*)d_in[16];
  const float* b1 = (const float*)d_in[17];
  const float* w2 = (const float*)d_in[18];
  const float* b2 = (const float*)d_in[19];

  char* base = (char*)d_ws;
  auto carve = [&](size_t bytes) {
    char* r = base;
    base += (bytes + 255) & ~(size_t)255;
    return r;
  };
  float* x            = (float*)carve((size_t)257 * E_DIM * 4);
  unsigned short* h   = (unsigned short*)carve((size_t)MPAD * E_DIM * 2);
  unsigned short* qb  = (unsigned short*)carve((size_t)16 * MPAD * 64 * 2);
  unsigned short* kbf = (unsigned short*)carve((size_t)16 * MPAD * 64 * 2);
  unsigned short* vTb = (unsigned short*)carve((size_t)16 * 64 * SPAD * 2);
  unsigned short* ob  = (unsigned short*)carve((size_t)MPAD * E_DIM * 2);
  unsigned short* mb  = (unsigned short*)carve((size_t)MPAD * FF_DIM * 2);
  float* part         = (float*)carve((size_t)4 * MPAD * E_DIM * 4);
  float* pbv          = (float*)carve(256 * 4);
  float* Mi           = (float*)carve(32 * 256 * 4);
  unsigned short* Pm  = (unsigned short*)carve((size_t)256 * KCP * 2);
  unsigned short* Wp  = (unsigned short*)carve((size_t)1024 * KCP * 2);

  prep_kernel<<<1280 + 512, 256, 0, stream>>>(frame, conv_w, Pm, Wp, h, ob, vTb);
  pb_cls_kernel<<<1, 256, 0, stream>>>(bboxes, cls_emb, pbv, Mi, x);
  conv_gemm<<<64, 256, 0, stream>>>(Pm, Wp, x);
  reduce_ln_kernel<<<257, 256, 0, stream>>>(x, nullptr, 0, nullptr, ln1_s, ln1_b, h);

  for (int l = 0; l < LAYERS; ++l) {
    size_t o2  = (size_t)l * E_DIM * E_DIM;
    size_t o1  = (size_t)l * E_DIM;
    size_t of1 = (size_t)l * E_DIM * FF_DIM;
    size_t ofb = (size_t)l * FF_DIM;
    // QKV: 192 items (nt 0..191 -> q/k/vT), K=1024 = 8 tiles
    gemm_nk<1024, 0, 8><<<192, 256, 0, stream>>>(h, E_DIM, wq + o2, wk + o2, wv + o2,
                                                 bq + o1, bk + o1, bv + o1,
                                                 192, qb, kbf, vTb, nullptr, nullptr);
    attn_kernel<<<272, 256, 0, stream>>>(qb, kbf, vTb, pbv, ob);
    // O-proj: 256 items = 64 nt x KS4 (chunk 256 = 2 tiles) -> fp32 partials
    gemm_nk<1024, 2, 2><<<256, 256, 0, stream>>>(ob, E_DIM, wo + o2, nullptr, nullptr,
                                                 nullptr, nullptr, nullptr,
                                                 64, nullptr, nullptr, nullptr, nullptr, part);
    reduce_ln_kernel<<<257, 256, 0, stream>>>(x, part, 4, bo + o1, ln2_s + o1, ln2_b + o1, h);
    // FF1: 256 items = 256 nt, K=1024 = 8 tiles; fused bias+quickgelu
    gemm_nk<4096, 1, 8><<<256, 256, 0, stream>>>(h, E_DIM, w1 + of1, nullptr, nullptr,
                                                 b1 + ofb, nullptr, nullptr,
                                                 256, nullptr, nullptr, nullptr, mb, nullptr);
    // FF2: 256 items = 64 nt x KS4 (chunk 1024 = 8 tiles) -> partials
    gemm_nk<1024, 2, 8><<<256, 256, 0, stream>>>(mb, FF_DIM, w2 + of1, nullptr, nullptr,
                                                 nullptr, nullptr, nullptr,
                                                 64, nullptr, nullptr, nullptr, nullptr, part);
    const float* nls = (l < LAYERS - 1) ? (ln1_s + (size_t)(l + 1) * E_DIM) : ln1_s;
    const float* nlb = (l < LAYERS - 1) ? (ln1_b + (size_t)(l + 1) * E_DIM) : ln1_b;
    reduce_ln_kernel<<<257, 256, 0, stream>>>(x, part, 4, b2 + o1, nls, nlb, h);
  }
  roi_kernel<<<33, 256, 0, stream>>>(x, Mi, (float*)d_out);
}